// Round 10
// baseline (629.313 us; speedup 1.0000x reference)
//
#include <hip/hip_runtime.h>
#include <math.h>

#define N_NODES 10000
#define N_EDGES 640000
#define OUT_CH  64
#define ELLW    192     // max in-degree slots; Poisson(64) max ~110, P[>192]~1e-19

#define CHUNKS  128
#define CHUNK_E 5000    // N_EDGES / CHUNKS exactly
#define GB      313     // ceil(10000/32) gemm tiles
#define NBLOCKS 512     // == min guaranteed capacity: VGPR<=256 (launch_bounds 256,2)
                        // gives >=2 blocks/CU, LDS 40KB gives 4/CU -> all co-resident

typedef unsigned long long ull;
typedef unsigned int uint;
typedef unsigned short ushort;
typedef unsigned char uchar;

#define FIXED_SCALE 262144.0f   // 2^18; count<<24 | fixed18(sum_w)

// ---------------- workspace layout (bytes) ----------------
// xw1b     : N*128 bf16   @ 0            (2,560,000)
// hb       : N*128 bf16   @  2,560,000   (2,560,000)   relu(h), bf16x2 packed
// xw2b     : N*64  bf16   @  5,120,000   (1,280,000)
// epack    : N*ELLW ull   @  6,400,000   (15,360,000)  (nrm_bits<<32 | src)
// blockcnt : CHUNKS*N u32 @ 21,760,000   (5,120,000)   (cnt<<24 | fixed18(sum_w))
// base8    : CHUNKS*N u8  @ 26,880,000   (1,280,000)
// rank8    : E u8         @ 28,160,000   (640,000)
// sd32     : E u32        @ 28,800,000   (2,560,000)   (dst<<16 | src)
// cnt_arr  : N int        @ 31,360,000   (40,000)
// dinv     : N f32        @ 31,400,000   (40,000)
// bar      : 8 int        @ 31,440,000   (32)          grid-barrier counters

__device__ __forceinline__ float bf_lo(uint u) { return __uint_as_float(u << 16); }
__device__ __forceinline__ float bf_hi(uint u) { return __uint_as_float(u & 0xffff0000u); }
__device__ __forceinline__ ushort f2bf(float v) {
    uint u = __float_as_uint(v);
    uint r = u + 0x7fffu + ((u >> 16) & 1u);   // round-to-nearest-even
    return (ushort)(r >> 16);
}

// Software grid barrier, one arrival counter per instance (no reset needed).
// threadfence = agent-scope fence (L2 wb / inv) -> plain stores from phase k
// are visible grid-wide in phase k+1, including across XCDs.
__device__ __forceinline__ void grid_barrier(int* __restrict__ bar, int idx) {
    __syncthreads();
    if (threadIdx.x == 0) {
        __threadfence();
        int prev = __hip_atomic_fetch_add(&bar[idx], 1, __ATOMIC_ACQ_REL,
                                          __HIP_MEMORY_SCOPE_AGENT);
        if (prev + 1 < NBLOCKS) {
            while (__hip_atomic_load(&bar[idx], __ATOMIC_ACQUIRE,
                                     __HIP_MEMORY_SCOPE_AGENT) < NBLOCKS)
                __builtin_amdgcn_s_sleep(2);
        }
        __threadfence();
    }
    __syncthreads();
}

__global__ __launch_bounds__(64) void init_bar_kernel(int* __restrict__ bar) {
    if (threadIdx.x < 8) bar[threadIdx.x] = 0;
}

// ---------- phase 1: chunk histograms (blocks [0,CHUNKS)) + gemm1 ----------
__device__ void phase1(int bid, const int* __restrict__ ei, const float* __restrict__ ew,
                       uchar* __restrict__ rank8, uint* __restrict__ sd32,
                       uint* __restrict__ blockcnt, const float* __restrict__ x,
                       const float* __restrict__ W1, ushort* __restrict__ xw1b,
                       uint* smem) {
    const int tid = threadIdx.x;
    if (bid < CHUNKS) {
        const int c = bid;
        __shared__ int sflag;
        if (tid == 0) sflag = 0;
        for (int i = tid; i < N_NODES; i += 256) smem[i] = 0u;
        __syncthreads();
        // layout self-detect: int64 LE [2,E] => sampled high dwords all zero
        int a = (tid < 64) ? ei[2 * (c * CHUNK_E + tid) + 1] : 0;
        if (a) atomicOr(&sflag, 1);
        __syncthreads();
        const int f = sflag;                     // 1 => int32 layout
        const ull* ei64 = (const ull*)ei;
        for (int k = tid; k < CHUNK_E; k += 256) {
            int e = c * CHUNK_E + k;
            int s, d;
            if (f) { s = ei[e];        d = ei[N_EDGES + e]; }
            else   { s = (int)ei64[e]; d = (int)ei64[N_EDGES + e]; }
            float w = ew[e];
            uint fx = (uint)(w * FIXED_SCALE + 0.5f);
            uint old = atomicAdd(&smem[d], (1u << 24) | fx);
            rank8[e] = (uchar)(old >> 24);
            sd32[e] = ((uint)d << 16) | (uint)s;
        }
        __syncthreads();
        for (int i = tid; i < N_NODES; i += 256)
            blockcnt[c * N_NODES + i] = smem[i];
    } else if (bid < CHUNKS + GB) {
        // gemm1: xw1b[32-row tile] = x @ W1 (f32 acc -> bf16)
        constexpr int K = 128, TM = 32, KT = 32, NCOL = 128, RPT = 16;
        float* sA = (float*)smem;           // [32][33]
        float* sB = sA + TM * (KT + 1);     // [32][128]
        int blk = bid - CHUNKS;
        int c = tid % NCOL, rr = tid / NCOL;
        int row0 = blk * TM;
        float acc[RPT];
#pragma unroll
        for (int r = 0; r < RPT; ++r) acc[r] = 0.0f;
        for (int k0 = 0; k0 < K; k0 += KT) {
            for (int i = tid; i < TM * KT; i += 256) {
                int r = i / KT, k = i % KT;
                int gr = row0 + r;
                sA[r * (KT + 1) + k] = (gr < N_NODES) ? x[gr * K + k0 + k] : 0.0f;
            }
            for (int i = tid; i < KT * NCOL; i += 256) {
                int k = i / NCOL, cc = i % NCOL;
                sB[k * NCOL + cc] = W1[(k0 + k) * NCOL + cc];
            }
            __syncthreads();
#pragma unroll
            for (int k = 0; k < KT; ++k) {
                float b = sB[k * NCOL + c];
#pragma unroll
                for (int r = 0; r < RPT; ++r)
                    acc[r] += sA[(rr * RPT + r) * (KT + 1) + k] * b;
            }
            __syncthreads();
        }
#pragma unroll
        for (int r = 0; r < RPT; ++r) {
            int gr = row0 + rr * RPT + r;
            if (gr < N_NODES) xw1b[gr * NCOL + c] = f2bf(acc[r]);
        }
    }
}

// ---------- phase 2: per-node scan over chunk histograms ----------
__device__ void phase2(int gid, const uint* __restrict__ blockcnt,
                       uchar* __restrict__ base8, int* __restrict__ cnt_arr,
                       float* __restrict__ dinv) {
    if (gid >= N_NODES) return;
    uint wsum = 0;
    int run = 0;
#pragma unroll 8
    for (int c = 0; c < CHUNKS; ++c) {
        uint v = blockcnt[c * N_NODES + gid];
        base8[c * N_NODES + gid] = (uchar)run;
        run += (int)(v >> 24);
        wsum += v & 0xffffffu;
    }
    cnt_arr[gid] = run;
    float dg = 1.0f + (float)wsum * (1.0f / FIXED_SCALE);
    dinv[gid] = (float)(1.0 / sqrt((double)dg));
}

// ---------- phase 3: atomic-free ELL fill ----------
__device__ void phase3(int gid, int stride, const uint* __restrict__ sd32,
                       const float* __restrict__ ew, const uchar* __restrict__ rank8,
                       const uchar* __restrict__ base8, const float* __restrict__ dinv,
                       ull* __restrict__ epack) {
    for (int e = gid; e < N_EDGES; e += stride) {
        uint sd = sd32[e];
        int s = (int)(sd & 0xffffu);
        int d = (int)(sd >> 16);
        int c = e / CHUNK_E;
        float nrm = dinv[s] * ew[e] * dinv[d];
        int slot = (int)base8[c * N_NODES + d] + (int)rank8[e];
        if (slot < ELLW)
            epack[d * ELLW + slot] = ((ull)__float_as_uint(nrm) << 32) | (ull)(uint)s;
    }
}

// ---------- phase 4: agg1 (wave per node, strided) -> hb bf16 (+bias,relu) ----------
__device__ void phase4(int bid, const ushort* __restrict__ xw1b,
                       const ull* __restrict__ epack, const int* __restrict__ cnt_arr,
                       const float* __restrict__ dinv, const float* __restrict__ b1,
                       uint* __restrict__ hb32) {
    const uint* __restrict__ xw32 = (const uint*)xw1b;   // row = 64 uints
    int l = threadIdx.x & 63;
    int wave = bid * 4 + (threadIdx.x >> 6);
    int totw = NBLOCKS * 4;
    for (int node = wave; node < N_NODES; node += totw) {
        int cnt = __builtin_amdgcn_readfirstlane(cnt_arr[node]);
        if (cnt > ELLW) cnt = ELLW;
        float dn = dinv[node];
        float d2 = dn * dn;
        uint su = xw32[node * 64 + l];
        float acc0 = d2 * bf_lo(su);
        float acc1 = d2 * bf_hi(su);
        const ull* ep = epack + (long)node * ELLW;
#pragma unroll 8
        for (int j = 0; j < cnt; ++j) {
            ull v = ep[j];                               // uniform address
            uint s = (uint)v;
            float n = __uint_as_float((uint)(v >> 32));
            uint u = xw32[s * 64 + l];                   // 256 B coalesced gather
            acc0 = fmaf(n, bf_lo(u), acc0);
            acc1 = fmaf(n, bf_hi(u), acc1);
        }
        float2 bb = ((const float2*)b1)[l];
        float o0 = fmaxf(acc0 + bb.x, 0.0f);
        float o1 = fmaxf(acc1 + bb.y, 0.0f);
        hb32[node * 64 + l] = ((uint)f2bf(o1) << 16) | (uint)f2bf(o0);
    }
}

// ---------- phase 5: gemm2 (hb bf16 @ W2 -> xw2b bf16), tiles strided ----------
__device__ void phase5(int bid, const uint* __restrict__ hb32,
                       const float* __restrict__ W2, ushort* __restrict__ xw2b,
                       uint* smem) {
    constexpr int K = 128, TM = 32, KT = 32, NCOL = 64, RPT = 8;
    float* sA = (float*)smem;           // [32][33]
    float* sB = sA + TM * (KT + 1);     // [32][64]
    const int tid = threadIdx.x;
    int c = tid % NCOL, rr = tid / NCOL;
    for (int blk = bid; blk < GB; blk += NBLOCKS) {
        int row0 = blk * TM;
        float acc[RPT];
#pragma unroll
        for (int r = 0; r < RPT; ++r) acc[r] = 0.0f;
        for (int k0 = 0; k0 < K; k0 += KT) {
            for (int i = tid; i < TM * (KT / 2); i += 256) {   // bf16x2 loads
                int r = i / (KT / 2), kk = i % (KT / 2);
                int gr = row0 + r;
                uint u = (gr < N_NODES) ? hb32[gr * 64 + (k0 >> 1) + kk] : 0u;
                sA[r * (KT + 1) + 2 * kk]     = bf_lo(u);
                sA[r * (KT + 1) + 2 * kk + 1] = bf_hi(u);
            }
            for (int i = tid; i < KT * NCOL; i += 256) {
                int k = i / NCOL, cc = i % NCOL;
                sB[k * NCOL + cc] = W2[(k0 + k) * NCOL + cc];
            }
            __syncthreads();
#pragma unroll
            for (int k = 0; k < KT; ++k) {
                float b = sB[k * NCOL + c];
#pragma unroll
                for (int r = 0; r < RPT; ++r)
                    acc[r] += sA[(rr * RPT + r) * (KT + 1) + k] * b;
            }
            __syncthreads();
        }
#pragma unroll
        for (int r = 0; r < RPT; ++r) {
            int gr = row0 + rr * RPT + r;
            if (gr < N_NODES) xw2b[gr * NCOL + c] = f2bf(acc[r]);
        }
    }
}

// ---------- phase 6: agg2 (wave per 2 nodes, strided) -> out f32 ----------
__device__ void phase6(int bid, const ushort* __restrict__ xw2b,
                       const ull* __restrict__ epack, const int* __restrict__ cnt_arr,
                       const float* __restrict__ dinv, const float* __restrict__ b2,
                       float* __restrict__ out) {
    const uint* __restrict__ xw32 = (const uint*)xw2b;   // row = 32 uints
    int lane = threadIdx.x & 63;
    int half = lane >> 5;
    int q = lane & 31;
    int wave = bid * 4 + (threadIdx.x >> 6);
    int totw = NBLOCKS * 4;
    for (int pair = wave; pair < N_NODES / 2; pair += totw) {
        int A = pair * 2, B = A + 1;
        int cntA = __builtin_amdgcn_readfirstlane(cnt_arr[A]);
        int cntB = __builtin_amdgcn_readfirstlane(cnt_arr[B]);
        if (cntA > ELLW) cntA = ELLW;
        if (cntB > ELLW) cntB = ELLW;
        int myn = half ? B : A;
        int mycnt = half ? cntB : cntA;
        float dn = dinv[myn];
        float d2 = dn * dn;
        uint su = xw32[myn * 32 + q];
        float acc0 = d2 * bf_lo(su);
        float acc1 = d2 * bf_hi(su);
        const ull* epA = epack + (long)A * ELLW;
        const ull* epB = epack + (long)B * ELLW;
        int mx = cntA > cntB ? cntA : cntB;
#pragma unroll 4
        for (int j = 0; j < mx; ++j) {
            ull vA = epA[j];                             // uniform address
            ull vB = epB[j];
            ull v = half ? vB : vA;
            uint s = (uint)v & 0xffffu;                  // clamp poison tails
            float n = (j < mycnt) ? __uint_as_float((uint)(v >> 32)) : 0.0f;
            uint u = xw32[s * 32 + q];
            acc0 = fmaf(n, bf_lo(u), acc0);
            acc1 = fmaf(n, bf_hi(u), acc1);
        }
        float2 bb = ((const float2*)b2)[q];
        float2 o;
        o.x = acc0 + bb.x;
        o.y = acc1 + bb.y;
        ((float2*)out)[myn * 32 + q] = o;
    }
}

// ============ persistent mega-kernel, plain launch + sw barriers ============
__global__ __launch_bounds__(256, 2) void mega_kernel(const int* ei, const float* ew,
                                                      const float* x, const float* W1,
                                                      const float* b1, const float* W2,
                                                      const float* b2, float* out,
                                                      ushort* xw1b, uint* hb32,
                                                      ushort* xw2b, ull* epack,
                                                      uint* blockcnt, uchar* base8,
                                                      uchar* rank8, uint* sd32,
                                                      int* cnt_arr, float* dinv,
                                                      int* bar) {
    __shared__ uint smem[10240];   // 40 KB, reused across phases
    const int bid = blockIdx.x;
    const int gid = bid * 256 + threadIdx.x;
    const int stride = NBLOCKS * 256;

    phase1(bid, ei, ew, rank8, sd32, blockcnt, x, W1, xw1b, smem);
    grid_barrier(bar, 0);
    phase2(gid, blockcnt, base8, cnt_arr, dinv);
    grid_barrier(bar, 1);
    phase3(gid, stride, sd32, ew, rank8, base8, dinv, epack);
    grid_barrier(bar, 2);
    phase4(bid, xw1b, epack, cnt_arr, dinv, b1, hb32);
    grid_barrier(bar, 3);
    phase5(bid, hb32, W2, xw2b, smem);
    grid_barrier(bar, 4);
    phase6(bid, xw2b, epack, cnt_arr, dinv, b2, out);
}

extern "C" void kernel_launch(void* const* d_in, const int* in_sizes, int n_in,
                              void* d_out, int out_size, void* d_ws, size_t ws_size,
                              hipStream_t stream) {
    const float* x  = (const float*)d_in[0];
    const int*   ei = (const int*)d_in[1];
    const float* ew = (const float*)d_in[2];
    const float* W1 = (const float*)d_in[3];
    const float* b1 = (const float*)d_in[4];
    const float* W2 = (const float*)d_in[5];
    const float* b2 = (const float*)d_in[6];
    float* out = (float*)d_out;

    char* ws = (char*)d_ws;
    ushort* xw1b    = (ushort*)(ws + 0);
    uint*   hb32    = (uint*)  (ws + 2560000);
    ushort* xw2b    = (ushort*)(ws + 5120000);
    ull*    epack   = (ull*)   (ws + 6400000);
    uint*   blockcnt= (uint*)  (ws + 21760000);
    uchar*  base8   = (uchar*) (ws + 26880000);
    uchar*  rank8   = (uchar*) (ws + 28160000);
    uint*   sd32    = (uint*)  (ws + 28800000);
    int*    cnt_arr = (int*)   (ws + 31360000);
    float*  dinv    = (float*) (ws + 31400000);
    int*    bar     = (int*)   (ws + 31440000);

    init_bar_kernel<<<1, 64, 0, stream>>>(bar);
    mega_kernel<<<NBLOCKS, 256, 0, stream>>>(ei, ew, x, W1, b1, W2, b2, out,
                                             xw1b, hb32, xw2b, epack, blockcnt,
                                             base8, rank8, sd32, cnt_arr, dinv, bar);
}